// Round 8
// baseline (1756.513 us; speedup 1.0000x reference)
//
#include <hip/hip_runtime.h>
#include <math.h>

#define Bn 128
#define Tn 512
#define Dn 32
#define Hn 128
#define Gn 512   // 4*H
#define Ln 3
#define MI 16    // items per scan block
#define CH 8     // ticks per staged chunk

// LDS-only barrier: does NOT drain vmcnt.
#define BAR_LDS() asm volatile("s_waitcnt lgkmcnt(0)\n\ts_barrier" ::: "memory")

typedef _Float16 h2 __attribute__((ext_vector_type(2)));
typedef _Float16 half4 __attribute__((ext_vector_type(4)));
typedef _Float16 half8 __attribute__((ext_vector_type(8)));   // MFMA A/B frag
typedef float f32x4 __attribute__((ext_vector_type(4)));      // MFMA acc

__device__ __forceinline__ float dot2(h2 a, h2 b, float c) {
    return __builtin_amdgcn_fdot2(a, b, c, false);
}
__device__ __forceinline__ h2 pkh(float a, float b) {
    h2 r; r.x = (_Float16)a; r.y = (_Float16)b; return r;
}
__device__ __forceinline__ float sigm(float x) {
    return __builtin_amdgcn_rcpf(1.f + __expf(-x));
}
__device__ __forceinline__ float tanh_fast(float x) {
    return 1.f - 2.f * __builtin_amdgcn_rcpf(1.f + __expf(2.f * x));
}

// ---------------------------------------------------------------------------
// fp32 -> fp16 convert (n multiple of 4)
// ---------------------------------------------------------------------------
__global__ __launch_bounds__(256) void cvt_f2h(
    const float* __restrict__ in, _Float16* __restrict__ out, int n)
{
    int base = (blockIdx.x * 256 + threadIdx.x) * 4;
    if (base < n) {
        float4 v = *(const float4*)(in + base);
        *(h2*)(out + base)     = pkh(v.x, v.y);
        *(h2*)(out + base + 2) = pkh(v.z, v.w);
    }
}

// ---------------------------------------------------------------------------
// fused_scan<K,RL>: batched-MFMA LSTM layer, ih-GEMM fused in.
// 8 blocks x 512 thr; block owns MI=16 items, wave w owns all 4 gates of
// units w*16..w*16+15.
// Per tick t: acc = bias; acc += Wih * inp[t]  (K/32 MFMAs per gate);
//             acc += Whh * h[t]               (4 MFMAs per gate);
// then in-lane activations (C layout: lane holds i,f,g,o of 4 units x its
// item), c-state in 4 regs, h written to double-buffered hL + global traj.
// inp rows staged global->LDS in CH-tick chunks, coalesced b128, padded
// row stride RL halves (conflict-free reads). Load-early/write-late dbuf.
// Verified fragment layouts (from gemm_pre_mfma / mfma_scan, both HW-passed):
// A[m=lane&15][k=(lane>>4)*8+j], B[k=(lane>>4)*8+j][n=lane&15],
// C row=(lane>>4)*4+reg, col=lane&15.
// ---------------------------------------------------------------------------
template<int K, int RL>
__global__ __launch_bounds__(512)
void fused_scan(
    const _Float16* __restrict__ inp,   // [B][Tn][K]  (xh or hs_prev)
    const _Float16* __restrict__ wih,   // [512][K]   fp16
    const _Float16* __restrict__ whh,   // [512][128] fp16
    const float* __restrict__ bih, const float* __restrict__ bhh, // [512]
    _Float16* __restrict__ hsout)       // [B][Tn][128] fp16
{
    const int tid  = threadIdx.x;
    const int w    = tid >> 6;
    const int lane = tid & 63;
    const int fm   = lane & 15;         // A row within tile / item / C col
    const int fq   = lane >> 4;         // k-quarter / C row group
    const int bi0  = blockIdx.x * MI;
    const int item = bi0 + fm;
    const int KS   = K / 32;            // k-steps of ih MFMA

    __shared__ __align__(16) _Float16 hL[2][MI][136];      // h dbuf
    __shared__ __align__(16) _Float16 pL[2][CH][MI][RL];   // input dbuf

    // A-frags: recurrent weights (4 gates x 4 k-steps)
    half8 ahh[4][4];
    #pragma unroll
    for (int g = 0; g < 4; g++)
        #pragma unroll
        for (int ks = 0; ks < 4; ks++)
            ahh[g][ks] = *(const half8*)(whh +
                (size_t)(g * Hn + w * 16 + fm) * Hn + ks * 32 + fq * 8);

    // A-frags: input weights (4 gates x KS k-steps)
    half8 aih[4][4];
    #pragma unroll
    for (int g = 0; g < 4; g++)
        #pragma unroll
        for (int ks = 0; ks < KS; ks++)
            aih[g][ks] = *(const half8*)(wih +
                (size_t)(g * Hn + w * 16 + fm) * K + ks * 32 + fq * 8);

    // bias seeds: C row = w*16 + fq*4 + r, 4 gates
    f32x4 bias4[4];
    #pragma unroll
    for (int g = 0; g < 4; g++)
        #pragma unroll
        for (int r = 0; r < 4; r++)
            bias4[g][r] = bih[g * Hn + w * 16 + fq * 4 + r] +
                          bhh[g * Hn + w * 16 + fq * 4 + r];

    for (int i = tid; i < 2 * MI * 136; i += 512)
        ((_Float16*)hL)[i] = (_Float16)0;

    // ---- staging: chunk c = rows c*CH .. c*CH+7, coalesced b128 ----
    const int NLD = (K == 128) ? 4 : 1;   // b128 loads per thread per chunk
    float4 stg[4];

    auto stage_load = [&](int c) {
        #pragma unroll
        for (int j = 0; j < NLD; j++) {
            int f = tid + j * 512;
            int r, it, colh;
            if (K == 128) { r = f >> 8; int rem = f & 255; it = rem >> 4; colh = (rem & 15) * 8; }
            else          { r = f >> 6; int rem = f & 63;  it = rem >> 2; colh = (rem & 3) * 8; }
            stg[j] = *(const float4*)(inp +
                ((size_t)(bi0 + it) * Tn + (c * CH + r)) * K + colh);
        }
    };
    auto stage_write = [&](int c) {
        #pragma unroll
        for (int j = 0; j < NLD; j++) {
            int f = tid + j * 512;
            int r, it, colh;
            if (K == 128) { r = f >> 8; int rem = f & 255; it = rem >> 4; colh = (rem & 15) * 8; }
            else          { r = f >> 6; int rem = f & 63;  it = rem >> 2; colh = (rem & 3) * 8; }
            *(float4*)&pL[c & 1][r][it][colh] = stg[j];
        }
    };

    // prologue: chunks 0,1 staged; hL zeroed
    stage_load(0); stage_write(0);
    stage_load(1); stage_write(1);
    __syncthreads();

    _Float16* hw = hsout + (size_t)item * Tn * Hn + w * 16 + fq * 4;
    float cst[4] = {0.f, 0.f, 0.f, 0.f};

    const int NCH = Tn / CH;   // 64
    for (int c = 0; c < NCH; c++) {
        const bool more = (c + 2 < NCH);
        if (more) stage_load(c + 2);

        #pragma unroll
        for (int tt = 0; tt < CH; tt++) {
            const _Float16* pr = &pL[c & 1][tt][fm][0];
            const _Float16* hr = &hL[tt & 1][fm][fq * 8];

            f32x4 acc[4];
            #pragma unroll
            for (int g = 0; g < 4; g++) acc[g] = bias4[g];

            // ih MFMAs (no dependence on h -> issue first, hide under chain)
            #pragma unroll
            for (int ks = 0; ks < KS; ks++) {
                half8 bf = *(const half8*)(pr + ks * 32 + fq * 8);
                #pragma unroll
                for (int g = 0; g < 4; g++)
                    acc[g] = __builtin_amdgcn_mfma_f32_16x16x32_f16(
                        aih[g][ks], bf, acc[g], 0, 0, 0);
            }

            // hh MFMAs
            half8 bf0 = *(const half8*)(hr);
            half8 bf1 = *(const half8*)(hr + 32);
            half8 bf2 = *(const half8*)(hr + 64);
            half8 bf3 = *(const half8*)(hr + 96);
            #pragma unroll
            for (int g = 0; g < 4; g++) {
                acc[g] = __builtin_amdgcn_mfma_f32_16x16x32_f16(ahh[g][0], bf0, acc[g], 0, 0, 0);
                acc[g] = __builtin_amdgcn_mfma_f32_16x16x32_f16(ahh[g][1], bf1, acc[g], 0, 0, 0);
                acc[g] = __builtin_amdgcn_mfma_f32_16x16x32_f16(ahh[g][2], bf2, acc[g], 0, 0, 0);
                acc[g] = __builtin_amdgcn_mfma_f32_16x16x32_f16(ahh[g][3], bf3, acc[g], 0, 0, 0);
            }

            half4 hh;
            #pragma unroll
            for (int r = 0; r < 4; r++) {
                float iv = sigm(acc[0][r]);
                float fv = sigm(acc[1][r]);
                float gv = tanh_fast(acc[2][r]);
                float ov = sigm(acc[3][r]);
                cst[r] = fv * cst[r] + iv * gv;
                hh[r] = (_Float16)(ov * tanh_fast(cst[r]));
            }
            *(half4*)&hL[(tt + 1) & 1][fm][w * 16 + fq * 4] = hh;
            *(half4*)hw = hh;
            hw += Hn;
            BAR_LDS();
        }

        // last tick's barrier guarantees all waves finished reading
        // buf[c&1]; chunk c+2 lands there. (compiler inserts vmcnt waits)
        if (more) stage_write(c + 2);
    }
}

// ---------------------------------------------------------------------------
// Attention pooling + MLP head (reads fp16 hs). One block per batch item.
// ---------------------------------------------------------------------------
__global__ __launch_bounds__(256) void head_kernel(
    const _Float16* __restrict__ hs16,
    const float* __restrict__ w_attn, const float* __restrict__ b_attn,
    const float* __restrict__ w1, const float* __restrict__ b1,
    const float* __restrict__ w2, const float* __restrict__ b2,
    float* __restrict__ out)
{
    const int b = blockIdx.x;
    const int tid = threadIdx.x;
    __shared__ h2 wa2[Hn / 2];
    __shared__ __align__(16) float sc[Tn];
    __shared__ __align__(16) float red[256];
    __shared__ __align__(16) float ctx_sh[Hn];
    __shared__ __align__(16) float h1_sh[64];

    if (tid < Hn / 2) wa2[tid] = pkh(w_attn[2 * tid], w_attn[2 * tid + 1]);
    __syncthreads();

    const _Float16* hb = hs16 + (size_t)b * Tn * Hn;

    for (int t = tid; t < Tn; t += 256) {
        const h2* hp = (const h2*)(hb + (size_t)t * Hn);
        float s = 0.f;
        #pragma unroll
        for (int k = 0; k < 64; k++) s = dot2(hp[k], wa2[k], s);
        sc[t] = s + b_attn[0];
    }
    __syncthreads();

    float m = fmaxf(sc[tid], sc[tid + 256]);
    red[tid] = m; __syncthreads();
    for (int s_ = 128; s_ > 0; s_ >>= 1) {
        if (tid < s_) red[tid] = fmaxf(red[tid], red[tid + s_]);
        __syncthreads();
    }
    float mx = red[0];
    __syncthreads();
    float e0 = __expf(sc[tid] - mx), e1 = __expf(sc[tid + 256] - mx);
    sc[tid] = e0; sc[tid + 256] = e1;
    red[tid] = e0 + e1; __syncthreads();
    for (int s_ = 128; s_ > 0; s_ >>= 1) {
        if (tid < s_) red[tid] += red[tid + s_];
        __syncthreads();
    }
    float inv = 1.f / red[0];
    __syncthreads();

    {
        int jj = tid & 127, half = tid >> 7;
        float a = 0.f;
        for (int t = half * 256; t < half * 256 + 256; t++)
            a += sc[t] * (float)hb[(size_t)t * Hn + jj];
        red[tid] = a;
        __syncthreads();
        if (tid < Hn) ctx_sh[tid] = (red[tid] + red[tid + Hn]) * inv;
        __syncthreads();
    }

    if (tid < 64) {
        const float4* wvv = (const float4*)(w1 + (size_t)tid * Hn);
        const float4* cv = (const float4*)ctx_sh;
        float s = 0.f;
        #pragma unroll
        for (int k = 0; k < 32; k++) {
            float4 a = wvv[k], c = cv[k];
            s += a.x * c.x + a.y * c.y + a.z * c.z + a.w * c.w;
        }
        h1_sh[tid] = fmaxf(s + b1[tid], 0.f);
    }
    __syncthreads();

    if (tid < 4) {
        float s = 0.f;
        const float* wvv = w2 + tid * 64;
        #pragma unroll
        for (int k = 0; k < 64; k++) s += wvv[k] * h1_sh[k];
        out[b * 4 + tid] = s + b2[tid];
    }
}

// ---------------------------------------------------------------------------
extern "C" void kernel_launch(void* const* d_in, const int* in_sizes, int n_in,
                              void* d_out, int out_size, void* d_ws, size_t ws_size,
                              hipStream_t stream)
{
    const float* x        = (const float*)d_in[0];
    const float* w_ih0    = (const float*)d_in[1];
    const float* w_ih_rest= (const float*)d_in[2];
    const float* w_hh     = (const float*)d_in[3];
    const float* b_ih     = (const float*)d_in[4];
    const float* b_hh     = (const float*)d_in[5];
    const float* w_attn   = (const float*)d_in[6];
    const float* b_attn   = (const float*)d_in[7];
    const float* w1       = (const float*)d_in[8];
    const float* b1       = (const float*)d_in[9];
    const float* w2       = (const float*)d_in[10];
    const float* b2       = (const float*)d_in[11];
    float* out = (float*)d_out;

    const size_t nX  = (size_t)Bn * Tn * Dn;       // 2,097,152
    const size_t nHS = (size_t)Bn * Tn * Hn;       // 8,388,608
    const size_t nW0 = (size_t)Gn * Dn;            // 16,384
    const size_t nWR = (size_t)(Ln - 1) * Gn * Hn; // 131,072
    const size_t nWH = (size_t)Ln * Gn * Hn;       // 196,608

    _Float16* xh    = (_Float16*)d_ws;
    _Float16* hs0   = xh + nX;
    _Float16* hs1   = hs0 + nHS;
    _Float16* hs2   = hs1 + nHS;
    _Float16* w0h   = hs2 + nHS;
    _Float16* wrh   = w0h + nW0;
    _Float16* whh16 = wrh + nWR;
    // total ~55 MB fp16

    cvt_f2h<<<(int)((nX / 4 + 255) / 256), 256, 0, stream>>>(x, xh, (int)nX);
    cvt_f2h<<<(int)((nW0 / 4 + 255) / 256), 256, 0, stream>>>(w_ih0, w0h, (int)nW0);
    cvt_f2h<<<(int)((nWR / 4 + 255) / 256), 256, 0, stream>>>(w_ih_rest, wrh, (int)nWR);
    cvt_f2h<<<(int)((nWH / 4 + 255) / 256), 256, 0, stream>>>(w_hh, whh16, (int)nWH);

    // layer 0: K=32 (x input)
    fused_scan<32, 40><<<Bn / MI, 512, 0, stream>>>(
        xh, w0h, whh16, b_ih, b_hh, hs0);
    // layer 1: K=128
    fused_scan<128, 136><<<Bn / MI, 512, 0, stream>>>(
        hs0, wrh, whh16 + (size_t)Gn * Hn,
        b_ih + Gn, b_hh + Gn, hs1);
    // layer 2: K=128
    fused_scan<128, 136><<<Bn / MI, 512, 0, stream>>>(
        hs1, wrh + (size_t)Gn * Hn, whh16 + 2 * (size_t)Gn * Hn,
        b_ih + 2 * Gn, b_hh + 2 * Gn, hs2);

    head_kernel<<<Bn, 256, 0, stream>>>(hs2, w_attn, b_attn, w1, b1, w2, b2, out);
}

// Round 10
// 1082.440 us; speedup vs baseline: 1.6227x; 1.6227x over previous
//
#include <hip/hip_runtime.h>
#include <math.h>

#define Bn 128
#define Tn 512
#define Dn 32
#define Hn 128
#define Gn 512   // 4*H
#define Ln 3

// LDS-only barrier: does NOT drain vmcnt.
#define BAR_LDS() asm volatile("s_waitcnt lgkmcnt(0)\n\ts_barrier" ::: "memory")

typedef _Float16 h2 __attribute__((ext_vector_type(2)));
typedef _Float16 half8 __attribute__((ext_vector_type(8)));   // MFMA A/B frag
typedef float f32x4 __attribute__((ext_vector_type(4)));      // MFMA acc

__device__ __forceinline__ float dot2(h2 a, h2 b, float c) {
    return __builtin_amdgcn_fdot2(a, b, c, false);
}
__device__ __forceinline__ h2 pkh(float a, float b) {
    h2 r; r.x = (_Float16)a; r.y = (_Float16)b; return r;
}
__device__ __forceinline__ float sigm(float x) {
    return __builtin_amdgcn_rcpf(1.f + __expf(-x));
}
__device__ __forceinline__ float tanh_fast(float x) {
    return 1.f - 2.f * __builtin_amdgcn_rcpf(1.f + __expf(2.f * x));
}

// pair-local butterfly add via DPP quad_perm(1,0,3,2): lanes 2i <-> 2i+1
#define DPPADD(a, CTRL) { \
    int _t = __builtin_amdgcn_update_dpp(0, __builtin_bit_cast(int, a), \
                                         CTRL, 0xF, 0xF, true); \
    a += __builtin_bit_cast(float, _t); }

#define KEEPH(x) asm volatile("" : "+v"(x))
#define LD8H(p) (*(const half8*)(p))
#define H2OF(V, i) (((const h2*)&(V))[i])

#define DECL16(P, R) \
  h2 P##0=pkh((R)[0],(R)[1]),   P##1=pkh((R)[2],(R)[3]),   P##2=pkh((R)[4],(R)[5]),   P##3=pkh((R)[6],(R)[7]),   \
     P##4=pkh((R)[8],(R)[9]),   P##5=pkh((R)[10],(R)[11]), P##6=pkh((R)[12],(R)[13]), P##7=pkh((R)[14],(R)[15]), \
     P##8=pkh((R)[16],(R)[17]), P##9=pkh((R)[18],(R)[19]), P##10=pkh((R)[20],(R)[21]),P##11=pkh((R)[22],(R)[23]),\
     P##12=pkh((R)[24],(R)[25]),P##13=pkh((R)[26],(R)[27]),P##14=pkh((R)[28],(R)[29]),P##15=pkh((R)[30],(R)[31]);
#define KEEP16(P) \
  KEEPH(P##0); KEEPH(P##1); KEEPH(P##2); KEEPH(P##3); KEEPH(P##4); KEEPH(P##5); \
  KEEPH(P##6); KEEPH(P##7); KEEPH(P##8); KEEPH(P##9); KEEPH(P##10); KEEPH(P##11); \
  KEEPH(P##12); KEEPH(P##13); KEEPH(P##14); KEEPH(P##15);

#define EXTRACT16(P, A, B, C, D) \
  h2 P##0 = H2OF(A,0), P##1 = H2OF(A,1), P##2  = H2OF(A,2), P##3  = H2OF(A,3), \
     P##4 = H2OF(B,0), P##5 = H2OF(B,1), P##6  = H2OF(B,2), P##7  = H2OF(B,3), \
     P##8 = H2OF(C,0), P##9 = H2OF(C,1), P##10 = H2OF(C,2), P##11 = H2OF(C,3), \
     P##12= H2OF(D,0), P##13= H2OF(D,1), P##14 = H2OF(D,2), P##15 = H2OF(D,3);

// all 4 gates against h-halves A and B
#define DOTA(j) { \
    aI = dot2(hvA##j, wiA##j, aI);  aF = dot2(hvA##j, wfA##j, aF); \
    aG = dot2(hvA##j, wgA##j, aG);  aO = dot2(hvA##j, woA##j, aO); }
#define DOTB(j) { \
    aI = dot2(hvB##j, wiB##j, aI);  aF = dot2(hvB##j, wfB##j, aF); \
    aG = dot2(hvB##j, wgB##j, aG);  aO = dot2(hvB##j, woB##j, aO); }

// ---------------------------------------------------------------------------
// fp32 -> fp16 convert (n multiple of 4)
// ---------------------------------------------------------------------------
__global__ __launch_bounds__(256) void cvt_f2h(
    const float* __restrict__ in, _Float16* __restrict__ out, int n)
{
    int base = (blockIdx.x * 256 + threadIdx.x) * 4;
    if (base < n) {
        float4 v = *(const float4*)(in + base);
        *(h2*)(out + base)     = pkh(v.x, v.y);
        *(h2*)(out + base + 2) = pkh(v.z, v.w);
    }
}

// ---------------------------------------------------------------------------
// MFMA GEMM: pre[M,512] = Ah[M,K] * Wh[512,K]^T + (b_ih + b_hh), fp16 output.
// Row m = b*512 + t. Verified fragment layouts (HW-passed R1-R8):
// A[m=lane&15][k=(lane>>4)*8+j], C/D row=(lane>>4)*4+reg, col=lane&15.
// ---------------------------------------------------------------------------
__global__ __launch_bounds__(256) void gemm_pre_mfma(
    const _Float16* __restrict__ A, int K, int rowStrideB, int t0, int tlog,
    const _Float16* __restrict__ W,
    const float* __restrict__ bi, const float* __restrict__ bh,
    _Float16* __restrict__ C)
{
    __shared__ h2 As2[64][20];
    __shared__ h2 Bs2[64][20];
    const int tid  = threadIdx.x;
    const int row0 = blockIdx.x * 64;
    const int col0 = blockIdx.y * 64;
    const int w    = tid >> 6;
    const int lane = tid & 63;
    const int qm   = (w >> 1) * 32;
    const int qn   = (w & 1) * 32;
    const int fm   = lane & 15;
    const int fq   = lane >> 4;
    const int tmask = (1 << tlog) - 1;
    const int lrow = tid >> 2;
    const int lk   = (tid & 3) * 8;

    f32x4 acc00 = {0,0,0,0}, acc01 = {0,0,0,0};
    f32x4 acc10 = {0,0,0,0}, acc11 = {0,0,0,0};

    for (int k0 = 0; k0 < K; k0 += 32) {
        {
            int rg = row0 + lrow;
            int b_idx = rg >> tlog, tt = rg & tmask;
            const _Float16* ap = A + (size_t)b_idx * rowStrideB +
                                 (size_t)(t0 + tt) * K + (k0 + lk);
            *(float4*)&As2[lrow][(tid & 3) * 4] = *(const float4*)ap;
            const _Float16* wp = W + (size_t)(col0 + lrow) * K + (k0 + lk);
            *(float4*)&Bs2[lrow][(tid & 3) * 4] = *(const float4*)wp;
        }
        __syncthreads();
        half8 a0 = *(const half8*)&As2[qm + fm][fq * 4];
        half8 a1 = *(const half8*)&As2[qm + 16 + fm][fq * 4];
        half8 b0 = *(const half8*)&Bs2[qn + fm][fq * 4];
        half8 b1 = *(const half8*)&Bs2[qn + 16 + fm][fq * 4];
        acc00 = __builtin_amdgcn_mfma_f32_16x16x32_f16(a0, b0, acc00, 0, 0, 0);
        acc01 = __builtin_amdgcn_mfma_f32_16x16x32_f16(a0, b1, acc01, 0, 0, 0);
        acc10 = __builtin_amdgcn_mfma_f32_16x16x32_f16(a1, b0, acc10, 0, 0, 0);
        acc11 = __builtin_amdgcn_mfma_f32_16x16x32_f16(a1, b1, acc11, 0, 0, 0);
        __syncthreads();
    }

    const int g0 = col0 + qn + fm;
    const int g1 = g0 + 16;
    const float bb0 = bi[g0] + bh[g0];
    const float bb1 = bi[g1] + bh[g1];
    const int m0 = row0 + qm + fq * 4;
    #pragma unroll
    for (int r = 0; r < 4; r++) {
        C[(size_t)(m0 + r) * Gn + g0]      = (_Float16)(acc00[r] + bb0);
        C[(size_t)(m0 + r) * Gn + g1]      = (_Float16)(acc01[r] + bb1);
        C[(size_t)(m0 + 16 + r) * Gn + g0] = (_Float16)(acc10[r] + bb0);
        C[(size_t)(m0 + 16 + r) * Gn + g1] = (_Float16)(acc11[r] + bb1);
    }
}

// ---------------------------------------------------------------------------
// scan256 v2: minimal-tick LSTM scan. 128 blocks x 256 threads = 1 wave/SIMD.
// Thread owns ONE unit u = wv*32 + (lane>>1), all 4 gates; k split 2-way
// across the lane pair (kq = lane&1 covers k in [64kq, 64kq+64)). 128 h2
// recurrent weights pinned in VGPRs; 128 fdot2/tick; 1-level DPP pair
// reduce; acts in-lane (c replicated x2). h double-buffered in LDS (reads
// are wave-broadcast -> conflict-free); ONE barrier/tick. pre (bias folded
// by gemm) prefetched 2 ticks ahead, MASKED by ms=(kq==0) so the pair
// butterfly counts it exactly once (R9 bug: both lanes seeded pre -> 2x).
// 80KB dead-guarded LDS pad forces 1 block/CU (R6-proven).
// ---------------------------------------------------------------------------
__global__ __launch_bounds__(256)
__attribute__((amdgpu_waves_per_eu(1, 2)))
void scan256(
    const _Float16* __restrict__ pre,   // [B*Tn, 512] fp16
    const float* __restrict__ w_hh,     // [512, 128] fp32 (this layer)
    _Float16* __restrict__ hs16)        // [B, Tn, 128] fp16 out
{
    const int b    = blockIdx.x;
    const int tid  = threadIdx.x;
    const int lane = tid & 63;
    const int wv   = tid >> 6;
    const int kq   = lane & 1;              // k-half
    const int u    = wv * 32 + (lane >> 1); // hidden unit (128 unique)

    __shared__ h2 hbuf[2][Hn / 2];
    __shared__ float lds_pad[20480];        // 80 KiB occupancy limiter

    if (pre == nullptr) {                   // never true; keeps pad live
        lds_pad[tid] = (float)tid;
        __syncthreads();
        ((float*)hs16)[tid] = lds_pad[(tid * 7) & 20479];
    }

    const float* rI = w_hh + (size_t)(0 * Hn + u) * Hn + kq * 64;
    const float* rF = w_hh + (size_t)(1 * Hn + u) * Hn + kq * 64;
    const float* rG = w_hh + (size_t)(2 * Hn + u) * Hn + kq * 64;
    const float* rO = w_hh + (size_t)(3 * Hn + u) * Hn + kq * 64;
    DECL16(wiA, rI) DECL16(wiB, (rI + 32))
    DECL16(wfA, rF) DECL16(wfB, (rF + 32))
    DECL16(wgA, rG) DECL16(wgB, (rG + 32))
    DECL16(woA, rO) DECL16(woB, (rO + 32))
    KEEP16(wiA) KEEP16(wiB) KEEP16(wfA) KEEP16(wfB)
    KEEP16(wgA) KEEP16(wgB) KEEP16(woA) KEEP16(woB)

    if (tid < Hn / 2) hbuf[0][tid] = pkh(0.f, 0.f);
    __syncthreads();

    const _Float16* pp = pre + (size_t)b * Tn * Gn + u;
    _Float16* hswr = hs16 + (size_t)b * Tn * Hn + u;

    // pre-mask: only the kq==0 lane of each pair carries the pre/bias seed
    // (pair butterfly sums both lanes' accumulators).
    const float ms = (kq == 0) ? 1.f : 0.f;

    // prefetch pre (4 gates) for t=0,1 (masked)
    float pI0 = ms * (float)pp[0],      pF0 = ms * (float)pp[Hn];
    float pG0 = ms * (float)pp[2 * Hn], pO0 = ms * (float)pp[3 * Hn];
    float pI1 = ms * (float)pp[Gn],     pF1 = ms * (float)pp[Gn + Hn];
    float pG1 = ms * (float)pp[Gn + 2 * Hn], pO1 = ms * (float)pp[Gn + 3 * Hn];
    const _Float16* pld = pp + 2 * (size_t)Gn;

    float cr = 0.f;

    auto body = [&](int t, float vI, float vF, float vG, float vO) {
        const h2* hrow = &hbuf[t & 1][kq * 32];
        half8 hA = LD8H(hrow);      half8 hB = LD8H(hrow + 4);
        half8 hC = LD8H(hrow + 8);  half8 hD = LD8H(hrow + 12);
        half8 hE = LD8H(hrow + 16); half8 hF_ = LD8H(hrow + 20);
        half8 hG_ = LD8H(hrow + 24); half8 hH_ = LD8H(hrow + 28);
        EXTRACT16(hvA, hA, hB, hC, hD)
        EXTRACT16(hvB, hE, hF_, hG_, hH_)

        float aI = vI, aF = vF, aG = vG, aO = vO;
        DOTA(0)  DOTA(1)  DOTA(2)  DOTA(3)
        DOTA(4)  DOTA(5)  DOTA(6)  DOTA(7)
        DOTA(8)  DOTA(9)  DOTA(10) DOTA(11)
        DOTA(12) DOTA(13) DOTA(14) DOTA(15)
        DOTB(0)  DOTB(1)  DOTB(2)  DOTB(3)
        DOTB(4)  DOTB(5)  DOTB(6)  DOTB(7)
        DOTB(8)  DOTB(9)  DOTB(10) DOTB(11)
        DOTB(12) DOTB(13) DOTB(14) DOTB(15)

        // pair butterfly: lanes 2i <-> 2i+1 (quad_perm(1,0,3,2) = 0xB1)
        DPPADD(aI, 0xB1) DPPADD(aF, 0xB1) DPPADD(aG, 0xB1) DPPADD(aO, 0xB1)

        float iv = sigm(aI);
        float fv = sigm(aF);
        float gv = tanh_fast(aG);
        float ov = sigm(aO);
        cr = fv * cr + iv * gv;
        float hnew = ov * tanh_fast(cr);
        _Float16 hh = (_Float16)hnew;
        if (kq == 0) {
            ((_Float16*)hbuf[(t + 1) & 1])[u] = hh;   // next-tick h
            *hswr = hh;                               // trajectory
        }
        hswr += Hn;
        BAR_LDS();
    };

    const int TN2 = Tn - 2;
    for (int t = 0; t < TN2; t++) {
        float vI = pI0, vF = pF0, vG = pG0, vO = pO0;
        pI0 = pI1; pF0 = pF1; pG0 = pG1; pO0 = pO1;
        pI1 = ms * (float)pld[0];      pF1 = ms * (float)pld[Hn];
        pG1 = ms * (float)pld[2 * Hn]; pO1 = ms * (float)pld[3 * Hn];
        pld += Gn;
        body(t, vI, vF, vG, vO);
    }
    {
        float vI = pI0, vF = pF0, vG = pG0, vO = pO0;
        pI0 = pI1; pF0 = pF1; pG0 = pG1; pO0 = pO1;
        body(TN2, vI, vF, vG, vO);
    }
    body(TN2 + 1, pI0, pF0, pG0, pO0);
}

// ---------------------------------------------------------------------------
// Attention pooling + MLP head (reads fp16 hs). One block per batch item.
// ---------------------------------------------------------------------------
__global__ __launch_bounds__(256) void head_kernel(
    const _Float16* __restrict__ hs16,
    const float* __restrict__ w_attn, const float* __restrict__ b_attn,
    const float* __restrict__ w1, const float* __restrict__ b1,
    const float* __restrict__ w2, const float* __restrict__ b2,
    float* __restrict__ out)
{
    const int b = blockIdx.x;
    const int tid = threadIdx.x;
    __shared__ h2 wa2[Hn / 2];
    __shared__ __align__(16) float sc[Tn];
    __shared__ __align__(16) float red[256];
    __shared__ __align__(16) float ctx_sh[Hn];
    __shared__ __align__(16) float h1_sh[64];

    if (tid < Hn / 2) wa2[tid] = pkh(w_attn[2 * tid], w_attn[2 * tid + 1]);
    __syncthreads();

    const _Float16* hb = hs16 + (size_t)b * Tn * Hn;

    for (int t = tid; t < Tn; t += 256) {
        const h2* hp = (const h2*)(hb + (size_t)t * Hn);
        float s = 0.f;
        #pragma unroll
        for (int k = 0; k < 64; k++) s = dot2(hp[k], wa2[k], s);
        sc[t] = s + b_attn[0];
    }
    __syncthreads();

    float m = fmaxf(sc[tid], sc[tid + 256]);
    red[tid] = m; __syncthreads();
    for (int s_ = 128; s_ > 0; s_ >>= 1) {
        if (tid < s_) red[tid] = fmaxf(red[tid], red[tid + s_]);
        __syncthreads();
    }
    float mx = red[0];
    __syncthreads();
    float e0 = __expf(sc[tid] - mx), e1 = __expf(sc[tid + 256] - mx);
    sc[tid] = e0; sc[tid + 256] = e1;
    red[tid] = e0 + e1; __syncthreads();
    for (int s_ = 128; s_ > 0; s_ >>= 1) {
        if (tid < s_) red[tid] += red[tid + s_];
        __syncthreads();
    }
    float inv = 1.f / red[0];
    __syncthreads();

    {
        int jj = tid & 127, half = tid >> 7;
        float a = 0.f;
        for (int t = half * 256; t < half * 256 + 256; t++)
            a += sc[t] * (float)hb[(size_t)t * Hn + jj];
        red[tid] = a;
        __syncthreads();
        if (tid < Hn) ctx_sh[tid] = (red[tid] + red[tid + Hn]) * inv;
        __syncthreads();
    }

    if (tid < 64) {
        const float4* wvv = (const float4*)(w1 + (size_t)tid * Hn);
        const float4* cv = (const float4*)ctx_sh;
        float s = 0.f;
        #pragma unroll
        for (int k = 0; k < 32; k++) {
            float4 a = wvv[k], c = cv[k];
            s += a.x * c.x + a.y * c.y + a.z * c.z + a.w * c.w;
        }
        h1_sh[tid] = fmaxf(s + b1[tid], 0.f);
    }
    __syncthreads();

    if (tid < 4) {
        float s = 0.f;
        const float* wvv = w2 + tid * 64;
        #pragma unroll
        for (int k = 0; k < 64; k++) s += wvv[k] * h1_sh[k];
        out[b * 4 + tid] = s + b2[tid];
    }
}

// ---------------------------------------------------------------------------
extern "C" void kernel_launch(void* const* d_in, const int* in_sizes, int n_in,
                              void* d_out, int out_size, void* d_ws, size_t ws_size,
                              hipStream_t stream)
{
    const float* x        = (const float*)d_in[0];
    const float* w_ih0    = (const float*)d_in[1];
    const float* w_ih_rest= (const float*)d_in[2];
    const float* w_hh     = (const float*)d_in[3];
    const float* b_ih     = (const float*)d_in[4];
    const float* b_hh     = (const float*)d_in[5];
    const float* w_attn   = (const float*)d_in[6];
    const float* b_attn   = (const float*)d_in[7];
    const float* w1       = (const float*)d_in[8];
    const float* b1       = (const float*)d_in[9];
    const float* w2       = (const float*)d_in[10];
    const float* b2       = (const float*)d_in[11];
    float* out = (float*)d_out;

    const size_t nX   = (size_t)Bn * Tn * Dn;       // 2,097,152
    const size_t nHS  = (size_t)Bn * Tn * Hn;       // 8,388,608
    const size_t nW0  = (size_t)Gn * Dn;            // 16,384
    const size_t nWR  = (size_t)(Ln - 1) * Gn * Hn; // 131,072
    const size_t nPRE = (size_t)Bn * Tn * Gn;       // 33,554,432 (fp16)

    _Float16* preh = (_Float16*)d_ws;
    _Float16* xh   = preh + nPRE;
    _Float16* hs0  = xh + nX;
    _Float16* hs1  = hs0 + nHS;
    _Float16* hs2  = hs1 + nHS;
    _Float16* w0h  = hs2 + nHS;
    _Float16* wrh  = w0h + nW0;
    // total ~122 MB

    cvt_f2h<<<(int)((nX / 4 + 255) / 256), 256, 0, stream>>>(x, xh, (int)nX);
    cvt_f2h<<<(int)((nW0 / 4 + 255) / 256), 256, 0, stream>>>(w_ih0, w0h, (int)nW0);
    cvt_f2h<<<(int)((nWR / 4 + 255) / 256), 256, 0, stream>>>(w_ih_rest, wrh, (int)nWR);

    for (int l = 0; l < Ln; l++) {
        const _Float16* A = (l == 0) ? xh : (l == 1 ? hs0 : hs1);
        int K = (l == 0) ? Dn : Hn;
        const _Float16* W = (l == 0) ? w0h : (wrh + (size_t)(l - 1) * Gn * Hn);
        _Float16* hsOut = (l == 0) ? hs0 : (l == 1 ? hs1 : hs2);

        gemm_pre_mfma<<<dim3(Bn * Tn / 64, 8), 256, 0, stream>>>(
            A, K, Tn * K, 0, 9, W, b_ih + l * Gn, b_hh + l * Gn, preh);
        scan256<<<Bn, 256, 0, stream>>>(
            preh, w_hh + (size_t)l * Gn * Hn, hsOut);
    }

    head_kernel<<<Bn, 256, 0, stream>>>(hs2, w_attn, b_attn, w1, b1, w2, b2, out);
}

// Round 11
// 1011.353 us; speedup vs baseline: 1.7368x; 1.0703x over previous
//
#include <hip/hip_runtime.h>
#include <math.h>

#define Bn 128
#define Tn 512
#define Dn 32
#define Hn 128
#define Gn 512   // 4*H
#define Ln 3

// LDS-only barrier: does NOT drain vmcnt.
#define BAR_LDS() asm volatile("s_waitcnt lgkmcnt(0)\n\ts_barrier" ::: "memory")

typedef _Float16 h2 __attribute__((ext_vector_type(2)));
typedef _Float16 half8 __attribute__((ext_vector_type(8)));   // MFMA A/B frag
typedef float f32x4 __attribute__((ext_vector_type(4)));      // MFMA acc

__device__ __forceinline__ float dot2(h2 a, h2 b, float c) {
    return __builtin_amdgcn_fdot2(a, b, c, false);
}
__device__ __forceinline__ h2 pkh(float a, float b) {
    h2 r; r.x = (_Float16)a; r.y = (_Float16)b; return r;
}
__device__ __forceinline__ float sigm(float x) {
    return __builtin_amdgcn_rcpf(1.f + __expf(-x));
}
__device__ __forceinline__ float tanh_fast(float x) {
    return 1.f - 2.f * __builtin_amdgcn_rcpf(1.f + __expf(2.f * x));
}

// pair-local butterfly add via DPP quad_perm(1,0,3,2): lanes 2i <-> 2i+1
#define DPPADD(a, CTRL) { \
    int _t = __builtin_amdgcn_update_dpp(0, __builtin_bit_cast(int, a), \
                                         CTRL, 0xF, 0xF, true); \
    a += __builtin_bit_cast(float, _t); }

#define KEEPH(x) asm volatile("" : "+v"(x))
#define LD8H(p) (*(const half8*)(p))
#define H2OF(V, i) (((const h2*)&(V))[i])

#define DECL16(P, R) \
  h2 P##0=pkh((R)[0],(R)[1]),   P##1=pkh((R)[2],(R)[3]),   P##2=pkh((R)[4],(R)[5]),   P##3=pkh((R)[6],(R)[7]),   \
     P##4=pkh((R)[8],(R)[9]),   P##5=pkh((R)[10],(R)[11]), P##6=pkh((R)[12],(R)[13]), P##7=pkh((R)[14],(R)[15]), \
     P##8=pkh((R)[16],(R)[17]), P##9=pkh((R)[18],(R)[19]), P##10=pkh((R)[20],(R)[21]),P##11=pkh((R)[22],(R)[23]),\
     P##12=pkh((R)[24],(R)[25]),P##13=pkh((R)[26],(R)[27]),P##14=pkh((R)[28],(R)[29]),P##15=pkh((R)[30],(R)[31]);
#define KEEP16(P) \
  KEEPH(P##0); KEEPH(P##1); KEEPH(P##2); KEEPH(P##3); KEEPH(P##4); KEEPH(P##5); \
  KEEPH(P##6); KEEPH(P##7); KEEPH(P##8); KEEPH(P##9); KEEPH(P##10); KEEPH(P##11); \
  KEEPH(P##12); KEEPH(P##13); KEEPH(P##14); KEEPH(P##15);

#define EXTRACT16(P, A, B, C, D) \
  h2 P##0 = H2OF(A,0), P##1 = H2OF(A,1), P##2  = H2OF(A,2), P##3  = H2OF(A,3), \
     P##4 = H2OF(B,0), P##5 = H2OF(B,1), P##6  = H2OF(B,2), P##7  = H2OF(B,3), \
     P##8 = H2OF(C,0), P##9 = H2OF(C,1), P##10 = H2OF(C,2), P##11 = H2OF(C,3), \
     P##12= H2OF(D,0), P##13= H2OF(D,1), P##14 = H2OF(D,2), P##15 = H2OF(D,3);

#define DOTA(j) { \
    aI = dot2(hvA##j, wiA##j, aI);  aF = dot2(hvA##j, wfA##j, aF); \
    aG = dot2(hvA##j, wgA##j, aG);  aO = dot2(hvA##j, woA##j, aO); }
#define DOTB(j) { \
    aI = dot2(hvB##j, wiB##j, aI);  aF = dot2(hvB##j, wfB##j, aF); \
    aG = dot2(hvB##j, wgB##j, aG);  aO = dot2(hvB##j, woB##j, aO); }

// ---------------------------------------------------------------------------
// MFMA GEMM with inline dtype conversion (removes standalone cvt kernels).
// TA = A dtype (float for layer 0's x / fp16 for hs), W always fp32.
// Output: PAIR-INTERLEAVED pre2[((m>>1)*Gn + g)*2 + (m&1)] so the scan
// loads one b32 per gate per TWO ticks. Fragment layouts HW-verified R1-R10.
// ---------------------------------------------------------------------------
template<typename TA>
__global__ __launch_bounds__(256) void gemm_pre(
    const TA* __restrict__ A, int K, int rowStrideB, int t0, int tlog,
    const float* __restrict__ W,
    const float* __restrict__ bi, const float* __restrict__ bh,
    _Float16* __restrict__ C)
{
    __shared__ h2 As2[64][20];
    __shared__ h2 Bs2[64][20];
    const int tid  = threadIdx.x;
    const int row0 = blockIdx.x * 64;
    const int col0 = blockIdx.y * 64;
    const int w    = tid >> 6;
    const int lane = tid & 63;
    const int qm   = (w >> 1) * 32;
    const int qn   = (w & 1) * 32;
    const int fm   = lane & 15;
    const int fq   = lane >> 4;
    const int tmask = (1 << tlog) - 1;
    const int lrow = tid >> 2;
    const int lk   = (tid & 3) * 8;

    f32x4 acc00 = {0,0,0,0}, acc01 = {0,0,0,0};
    f32x4 acc10 = {0,0,0,0}, acc11 = {0,0,0,0};

    for (int k0 = 0; k0 < K; k0 += 32) {
        {
            int rg = row0 + lrow;
            int b_idx = rg >> tlog, tt = rg & tmask;
            const TA* ap = A + (size_t)b_idx * rowStrideB +
                           (size_t)(t0 + tt) * K + (k0 + lk);
            if constexpr (sizeof(TA) == 2) {
                *(float4*)&As2[lrow][(tid & 3) * 4] = *(const float4*)ap;
            } else {
                float4 va = *(const float4*)ap;
                float4 vb = *(const float4*)(ap + 4);
                float4 o;
                ((h2*)&o)[0] = pkh(va.x, va.y);
                ((h2*)&o)[1] = pkh(va.z, va.w);
                ((h2*)&o)[2] = pkh(vb.x, vb.y);
                ((h2*)&o)[3] = pkh(vb.z, vb.w);
                *(float4*)&As2[lrow][(tid & 3) * 4] = o;
            }
            const float* wp = W + (size_t)(col0 + lrow) * K + (k0 + lk);
            float4 wa = *(const float4*)wp;
            float4 wb = *(const float4*)(wp + 4);
            float4 ow;
            ((h2*)&ow)[0] = pkh(wa.x, wa.y);
            ((h2*)&ow)[1] = pkh(wa.z, wa.w);
            ((h2*)&ow)[2] = pkh(wb.x, wb.y);
            ((h2*)&ow)[3] = pkh(wb.z, wb.w);
            *(float4*)&Bs2[lrow][(tid & 3) * 4] = ow;
        }
        __syncthreads();
        half8 a0 = *(const half8*)&As2[qm + fm][fq * 4];
        half8 a1 = *(const half8*)&As2[qm + 16 + fm][fq * 4];
        half8 b0 = *(const half8*)&Bs2[qn + fm][fq * 4];
        half8 b1 = *(const half8*)&Bs2[qn + 16 + fm][fq * 4];
        acc00 = __builtin_amdgcn_mfma_f32_16x16x32_f16(a0, b0, acc00, 0, 0, 0);
        acc01 = __builtin_amdgcn_mfma_f32_16x16x32_f16(a0, b1, acc01, 0, 0, 0);
        acc10 = __builtin_amdgcn_mfma_f32_16x16x32_f16(a1, b0, acc10, 0, 0, 0);
        acc11 = __builtin_amdgcn_mfma_f32_16x16x32_f16(a1, b1, acc11, 0, 0, 0);
        __syncthreads();
    }

    const int g0 = col0 + qn + fm;
    const int g1 = g0 + 16;
    const float bb0 = bi[g0] + bh[g0];
    const float bb1 = bi[g1] + bh[g1];
    const int m0 = row0 + qm + fq * 4;
    #pragma unroll
    for (int r = 0; r < 4; r++) {
        int ma = m0 + r, mb = m0 + 16 + r;
        C[((size_t)(ma >> 1) * Gn + g0) * 2 + (ma & 1)] = (_Float16)(acc00[r] + bb0);
        C[((size_t)(ma >> 1) * Gn + g1) * 2 + (ma & 1)] = (_Float16)(acc01[r] + bb1);
        C[((size_t)(mb >> 1) * Gn + g0) * 2 + (mb & 1)] = (_Float16)(acc10[r] + bb0);
        C[((size_t)(mb >> 1) * Gn + g1) * 2 + (mb & 1)] = (_Float16)(acc11[r] + bb1);
    }
}

// ---------------------------------------------------------------------------
// scan256 v3: R10's verified structure + paired-pre loads (4 b32 loads per
// TWO ticks instead of 8 scalar loads) to cut per-tick vmem issue / vmcnt
// pressure on the serial tick path.
// ---------------------------------------------------------------------------
__global__ __launch_bounds__(256)
__attribute__((amdgpu_waves_per_eu(1, 2)))
void scan256(
    const _Float16* __restrict__ pre,   // pre2 pair-interleaved, fp16
    const float* __restrict__ w_hh,     // [512, 128] fp32 (this layer)
    _Float16* __restrict__ hs16)        // [B, Tn, 128] fp16 out
{
    const int b    = blockIdx.x;
    const int tid  = threadIdx.x;
    const int lane = tid & 63;
    const int wv   = tid >> 6;
    const int kq   = lane & 1;              // k-half
    const int u    = wv * 32 + (lane >> 1); // hidden unit (128 unique)

    __shared__ h2 hbuf[2][Hn / 2];
    __shared__ float lds_pad[20480];        // 80 KiB occupancy limiter

    if (pre == nullptr) {                   // never true; keeps pad live
        lds_pad[tid] = (float)tid;
        __syncthreads();
        ((float*)hs16)[tid] = lds_pad[(tid * 7) & 20479];
    }

    const float* rI = w_hh + (size_t)(0 * Hn + u) * Hn + kq * 64;
    const float* rF = w_hh + (size_t)(1 * Hn + u) * Hn + kq * 64;
    const float* rG = w_hh + (size_t)(2 * Hn + u) * Hn + kq * 64;
    const float* rO = w_hh + (size_t)(3 * Hn + u) * Hn + kq * 64;
    DECL16(wiA, rI) DECL16(wiB, (rI + 32))
    DECL16(wfA, rF) DECL16(wfB, (rF + 32))
    DECL16(wgA, rG) DECL16(wgB, (rG + 32))
    DECL16(woA, rO) DECL16(woB, (rO + 32))
    KEEP16(wiA) KEEP16(wiB) KEEP16(wfA) KEEP16(wfB)
    KEEP16(wgA) KEEP16(wgB) KEEP16(woA) KEEP16(woB)

    if (tid < Hn / 2) hbuf[0][tid] = pkh(0.f, 0.f);
    __syncthreads();

    // pair-view of pre2: qq[pr*Gn + g*128] = h2{tick 2pr, tick 2pr+1}
    const h2* qq = (const h2*)pre + (size_t)(b * 256) * Gn + u;
    _Float16* hswr = hs16 + (size_t)b * Tn * Hn + u;

    // pre-mask: only the kq==0 lane of each pair carries the pre/bias seed
    const float ms = (kq == 0) ? 1.f : 0.f;

    h2 qI0 = qq[0],        qF0 = qq[128],      qG0 = qq[256],      qO0 = qq[384];
    h2 qI1 = qq[Gn],       qF1 = qq[Gn + 128], qG1 = qq[Gn + 256], qO1 = qq[Gn + 384];
    const h2* pld = qq + 2 * (size_t)Gn;

    float cr = 0.f;

    auto body = [&](int t, float vI, float vF, float vG, float vO) {
        const h2* hrow = &hbuf[t & 1][kq * 32];
        half8 hA = LD8H(hrow);      half8 hB = LD8H(hrow + 4);
        half8 hC = LD8H(hrow + 8);  half8 hD = LD8H(hrow + 12);
        half8 hE = LD8H(hrow + 16); half8 hF_ = LD8H(hrow + 20);
        half8 hG_ = LD8H(hrow + 24); half8 hH_ = LD8H(hrow + 28);
        EXTRACT16(hvA, hA, hB, hC, hD)
        EXTRACT16(hvB, hE, hF_, hG_, hH_)

        float aI = vI, aF = vF, aG = vG, aO = vO;
        DOTA(0)  DOTA(1)  DOTA(2)  DOTA(3)
        DOTA(4)  DOTA(5)  DOTA(6)  DOTA(7)
        DOTA(8)  DOTA(9)  DOTA(10) DOTA(11)
        DOTA(12) DOTA(13) DOTA(14) DOTA(15)
        DOTB(0)  DOTB(1)  DOTB(2)  DOTB(3)
        DOTB(4)  DOTB(5)  DOTB(6)  DOTB(7)
        DOTB(8)  DOTB(9)  DOTB(10) DOTB(11)
        DOTB(12) DOTB(13) DOTB(14) DOTB(15)

        DPPADD(aI, 0xB1) DPPADD(aF, 0xB1) DPPADD(aG, 0xB1) DPPADD(aO, 0xB1)

        float iv = sigm(aI);
        float fv = sigm(aF);
        float gv = tanh_fast(aG);
        float ov = sigm(aO);
        cr = fv * cr + iv * gv;
        float hnew = ov * tanh_fast(cr);
        _Float16 hh = (_Float16)hnew;
        if (kq == 0) {
            ((_Float16*)hbuf[(t + 1) & 1])[u] = hh;
            *hswr = hh;
        }
        hswr += Hn;
        BAR_LDS();
    };

    for (int pr = 0; pr < 254; pr++) {
        body(2 * pr,     ms * (float)qI0.x, ms * (float)qF0.x,
                         ms * (float)qG0.x, ms * (float)qO0.x);
        body(2 * pr + 1, ms * (float)qI0.y, ms * (float)qF0.y,
                         ms * (float)qG0.y, ms * (float)qO0.y);
        qI0 = qI1; qF0 = qF1; qG0 = qG1; qO0 = qO1;
        qI1 = pld[0]; qF1 = pld[128]; qG1 = pld[256]; qO1 = pld[384];
        pld += Gn;
    }
    body(508, ms * (float)qI0.x, ms * (float)qF0.x,
              ms * (float)qG0.x, ms * (float)qO0.x);
    body(509, ms * (float)qI0.y, ms * (float)qF0.y,
              ms * (float)qG0.y, ms * (float)qO0.y);
    qI0 = qI1; qF0 = qF1; qG0 = qG1; qO0 = qO1;
    body(510, ms * (float)qI0.x, ms * (float)qF0.x,
              ms * (float)qG0.x, ms * (float)qO0.x);
    body(511, ms * (float)qI0.y, ms * (float)qF0.y,
              ms * (float)qG0.y, ms * (float)qO0.y);
}

// ---------------------------------------------------------------------------
// Attention pooling + MLP head (reads fp16 hs). One block per batch item.
// ---------------------------------------------------------------------------
__global__ __launch_bounds__(256) void head_kernel(
    const _Float16* __restrict__ hs16,
    const float* __restrict__ w_attn, const float* __restrict__ b_attn,
    const float* __restrict__ w1, const float* __restrict__ b1,
    const float* __restrict__ w2, const float* __restrict__ b2,
    float* __restrict__ out)
{
    const int b = blockIdx.x;
    const int tid = threadIdx.x;
    __shared__ h2 wa2[Hn / 2];
    __shared__ __align__(16) float sc[Tn];
    __shared__ __align__(16) float red[256];
    __shared__ __align__(16) float ctx_sh[Hn];
    __shared__ __align__(16) float h1_sh[64];

    if (tid < Hn / 2) wa2[tid] = pkh(w_attn[2 * tid], w_attn[2 * tid + 1]);
    __syncthreads();

    const _Float16* hb = hs16 + (size_t)b * Tn * Hn;

    for (int t = tid; t < Tn; t += 256) {
        const h2* hp = (const h2*)(hb + (size_t)t * Hn);
        float s = 0.f;
        #pragma unroll
        for (int k = 0; k < 64; k++) s = dot2(hp[k], wa2[k], s);
        sc[t] = s + b_attn[0];
    }
    __syncthreads();

    float m = fmaxf(sc[tid], sc[tid + 256]);
    red[tid] = m; __syncthreads();
    for (int s_ = 128; s_ > 0; s_ >>= 1) {
        if (tid < s_) red[tid] = fmaxf(red[tid], red[tid + s_]);
        __syncthreads();
    }
    float mx = red[0];
    __syncthreads();
    float e0 = __expf(sc[tid] - mx), e1 = __expf(sc[tid + 256] - mx);
    sc[tid] = e0; sc[tid + 256] = e1;
    red[tid] = e0 + e1; __syncthreads();
    for (int s_ = 128; s_ > 0; s_ >>= 1) {
        if (tid < s_) red[tid] += red[tid + s_];
        __syncthreads();
    }
    float inv = 1.f / red[0];
    __syncthreads();

    {
        int jj = tid & 127, half = tid >> 7;
        float a = 0.f;
        for (int t = half * 256; t < half * 256 + 256; t++)
            a += sc[t] * (float)hb[(size_t)t * Hn + jj];
        red[tid] = a;
        __syncthreads();
        if (tid < Hn) ctx_sh[tid] = (red[tid] + red[tid + Hn]) * inv;
        __syncthreads();
    }

    if (tid < 64) {
        const float4* wvv = (const float4*)(w1 + (size_t)tid * Hn);
        const float4* cv = (const float4*)ctx_sh;
        float s = 0.f;
        #pragma unroll
        for (int k = 0; k < 32; k++) {
            float4 a = wvv[k], c = cv[k];
            s += a.x * c.x + a.y * c.y + a.z * c.z + a.w * c.w;
        }
        h1_sh[tid] = fmaxf(s + b1[tid], 0.f);
    }
    __syncthreads();

    if (tid < 4) {
        float s = 0.f;
        const float* wvv = w2 + tid * 64;
        #pragma unroll
        for (int k = 0; k < 64; k++) s += wvv[k] * h1_sh[k];
        out[b * 4 + tid] = s + b2[tid];
    }
}

// ---------------------------------------------------------------------------
extern "C" void kernel_launch(void* const* d_in, const int* in_sizes, int n_in,
                              void* d_out, int out_size, void* d_ws, size_t ws_size,
                              hipStream_t stream)
{
    const float* x        = (const float*)d_in[0];
    const float* w_ih0    = (const float*)d_in[1];
    const float* w_ih_rest= (const float*)d_in[2];
    const float* w_hh     = (const float*)d_in[3];
    const float* b_ih     = (const float*)d_in[4];
    const float* b_hh     = (const float*)d_in[5];
    const float* w_attn   = (const float*)d_in[6];
    const float* b_attn   = (const float*)d_in[7];
    const float* w1       = (const float*)d_in[8];
    const float* b1       = (const float*)d_in[9];
    const float* w2       = (const float*)d_in[10];
    const float* b2       = (const float*)d_in[11];
    float* out = (float*)d_out;

    const size_t nHS  = (size_t)Bn * Tn * Hn;       // 8,388,608
    const size_t nPRE = (size_t)Bn * Tn * Gn;       // 33,554,432 (fp16)

    _Float16* preh = (_Float16*)d_ws;
    _Float16* hs0  = preh + nPRE;
    _Float16* hs1  = hs0 + nHS;
    _Float16* hs2  = hs1 + nHS;
    // total ~117 MB fp16

    // layer 0: A = x (fp32, converted inline), W = w_ih0 (fp32)
    gemm_pre<float><<<dim3(Bn * Tn / 64, 8), 256, 0, stream>>>(
        x, Dn, Tn * Dn, 0, 9, w_ih0, b_ih, b_hh, preh);
    scan256<<<Bn, 256, 0, stream>>>(preh, w_hh, hs0);

    // layer 1: A = hs0 (fp16), W = w_ih_rest[0] (fp32)
    gemm_pre<_Float16><<<dim3(Bn * Tn / 64, 8), 256, 0, stream>>>(
        hs0, Hn, Tn * Hn, 0, 9, w_ih_rest,
        b_ih + Gn, b_hh + Gn, preh);
    scan256<<<Bn, 256, 0, stream>>>(preh, w_hh + (size_t)Gn * Hn, hs1);

    // layer 2: A = hs1 (fp16), W = w_ih_rest[1] (fp32)
    gemm_pre<_Float16><<<dim3(Bn * Tn / 64, 8), 256, 0, stream>>>(
        hs1, Hn, Tn * Hn, 0, 9, w_ih_rest + (size_t)Gn * Hn,
        b_ih + 2 * Gn, b_hh + 2 * Gn, preh);
    scan256<<<Bn, 256, 0, stream>>>(preh, w_hh + 2 * (size_t)Gn * Hn, hs2);

    head_kernel<<<Bn, 256, 0, stream>>>(hs2, w_attn, b_attn, w1, b1, w2, b2, out);
}

// Round 12
// 991.310 us; speedup vs baseline: 1.7719x; 1.0202x over previous
//
#include <hip/hip_runtime.h>
#include <math.h>

#define Bn 128
#define Tn 512
#define Dn 32
#define Hn 128
#define Gn 512   // 4*H
#define Ln 3

// LDS-only barrier: does NOT drain vmcnt.
#define BAR_LDS() asm volatile("s_waitcnt lgkmcnt(0)\n\ts_barrier" ::: "memory")

typedef _Float16 h2 __attribute__((ext_vector_type(2)));
typedef _Float16 h4 __attribute__((ext_vector_type(4)));
typedef _Float16 half8 __attribute__((ext_vector_type(8)));   // MFMA A/B frag
typedef float f32x4 __attribute__((ext_vector_type(4)));      // MFMA acc

__device__ __forceinline__ float dot2(h2 a, h2 b, float c) {
    return __builtin_amdgcn_fdot2(a, b, c, false);
}
__device__ __forceinline__ h2 pkh(float a, float b) {
    h2 r; r.x = (_Float16)a; r.y = (_Float16)b; return r;
}
__device__ __forceinline__ float sigm(float x) {
    return __builtin_amdgcn_rcpf(1.f + __expf(-x));
}
__device__ __forceinline__ float tanh_fast(float x) {
    return 1.f - 2.f * __builtin_amdgcn_rcpf(1.f + __expf(2.f * x));
}

// pair-local butterfly add via DPP quad_perm(1,0,3,2): lanes 2i <-> 2i+1
#define DPPADD(a, CTRL) { \
    int _t = __builtin_amdgcn_update_dpp(0, __builtin_bit_cast(int, a), \
                                         CTRL, 0xF, 0xF, true); \
    a += __builtin_bit_cast(float, _t); }

#define KEEPH(x) asm volatile("" : "+v"(x))
#define LD8H(p) (*(const half8*)(p))
#define H2OF(V, i) (((const h2*)&(V))[i])

#define DECL16(P, R) \
  h2 P##0=pkh((R)[0],(R)[1]),   P##1=pkh((R)[2],(R)[3]),   P##2=pkh((R)[4],(R)[5]),   P##3=pkh((R)[6],(R)[7]),   \
     P##4=pkh((R)[8],(R)[9]),   P##5=pkh((R)[10],(R)[11]), P##6=pkh((R)[12],(R)[13]), P##7=pkh((R)[14],(R)[15]), \
     P##8=pkh((R)[16],(R)[17]), P##9=pkh((R)[18],(R)[19]), P##10=pkh((R)[20],(R)[21]),P##11=pkh((R)[22],(R)[23]),\
     P##12=pkh((R)[24],(R)[25]),P##13=pkh((R)[26],(R)[27]),P##14=pkh((R)[28],(R)[29]),P##15=pkh((R)[30],(R)[31]);
#define KEEP16(P) \
  KEEPH(P##0); KEEPH(P##1); KEEPH(P##2); KEEPH(P##3); KEEPH(P##4); KEEPH(P##5); \
  KEEPH(P##6); KEEPH(P##7); KEEPH(P##8); KEEPH(P##9); KEEPH(P##10); KEEPH(P##11); \
  KEEPH(P##12); KEEPH(P##13); KEEPH(P##14); KEEPH(P##15);

#define EXTRACT16(P, A, B, C, D) \
  h2 P##0 = H2OF(A,0), P##1 = H2OF(A,1), P##2  = H2OF(A,2), P##3  = H2OF(A,3), \
     P##4 = H2OF(B,0), P##5 = H2OF(B,1), P##6  = H2OF(B,2), P##7  = H2OF(B,3), \
     P##8 = H2OF(C,0), P##9 = H2OF(C,1), P##10 = H2OF(C,2), P##11 = H2OF(C,3), \
     P##12= H2OF(D,0), P##13= H2OF(D,1), P##14 = H2OF(D,2), P##15 = H2OF(D,3);

#define DOTA(j) { \
    aI = dot2(hvA##j, wiA##j, aI);  aF = dot2(hvA##j, wfA##j, aF); \
    aG = dot2(hvA##j, wgA##j, aG);  aO = dot2(hvA##j, woA##j, aO); }
#define DOTB(j) { \
    aI = dot2(hvB##j, wiB##j, aI);  aF = dot2(hvB##j, wfB##j, aF); \
    aG = dot2(hvB##j, wgB##j, aG);  aO = dot2(hvB##j, woB##j, aO); }

// ---------------------------------------------------------------------------
// MFMA GEMM with inline dtype conversion. TA = A dtype (fp32 x / fp16 hs),
// W always fp32. Output: QUAD-INTERLEAVED pre4[((m>>2)*Gn + g)*4 + (m&3)]
// so the scan loads one b64 per gate per FOUR ticks. Layouts HW-verified.
// ---------------------------------------------------------------------------
template<typename TA>
__global__ __launch_bounds__(256) void gemm_pre(
    const TA* __restrict__ A, int K, int rowStrideB, int t0, int tlog,
    const float* __restrict__ W,
    const float* __restrict__ bi, const float* __restrict__ bh,
    _Float16* __restrict__ C)
{
    __shared__ h2 As2[64][20];
    __shared__ h2 Bs2[64][20];
    const int tid  = threadIdx.x;
    const int row0 = blockIdx.x * 64;
    const int col0 = blockIdx.y * 64;
    const int w    = tid >> 6;
    const int lane = tid & 63;
    const int qm   = (w >> 1) * 32;
    const int qn   = (w & 1) * 32;
    const int fm   = lane & 15;
    const int fq   = lane >> 4;
    const int tmask = (1 << tlog) - 1;
    const int lrow = tid >> 2;
    const int lk   = (tid & 3) * 8;

    f32x4 acc00 = {0,0,0,0}, acc01 = {0,0,0,0};
    f32x4 acc10 = {0,0,0,0}, acc11 = {0,0,0,0};

    for (int k0 = 0; k0 < K; k0 += 32) {
        {
            int rg = row0 + lrow;
            int b_idx = rg >> tlog, tt = rg & tmask;
            const TA* ap = A + (size_t)b_idx * rowStrideB +
                           (size_t)(t0 + tt) * K + (k0 + lk);
            if constexpr (sizeof(TA) == 2) {
                *(float4*)&As2[lrow][(tid & 3) * 4] = *(const float4*)ap;
            } else {
                float4 va = *(const float4*)ap;
                float4 vb = *(const float4*)(ap + 4);
                float4 o;
                ((h2*)&o)[0] = pkh(va.x, va.y);
                ((h2*)&o)[1] = pkh(va.z, va.w);
                ((h2*)&o)[2] = pkh(vb.x, vb.y);
                ((h2*)&o)[3] = pkh(vb.z, vb.w);
                *(float4*)&As2[lrow][(tid & 3) * 4] = o;
            }
            const float* wp = W + (size_t)(col0 + lrow) * K + (k0 + lk);
            float4 wa = *(const float4*)wp;
            float4 wb = *(const float4*)(wp + 4);
            float4 ow;
            ((h2*)&ow)[0] = pkh(wa.x, wa.y);
            ((h2*)&ow)[1] = pkh(wa.z, wa.w);
            ((h2*)&ow)[2] = pkh(wb.x, wb.y);
            ((h2*)&ow)[3] = pkh(wb.z, wb.w);
            *(float4*)&Bs2[lrow][(tid & 3) * 4] = ow;
        }
        __syncthreads();
        half8 a0 = *(const half8*)&As2[qm + fm][fq * 4];
        half8 a1 = *(const half8*)&As2[qm + 16 + fm][fq * 4];
        half8 b0 = *(const half8*)&Bs2[qn + fm][fq * 4];
        half8 b1 = *(const half8*)&Bs2[qn + 16 + fm][fq * 4];
        acc00 = __builtin_amdgcn_mfma_f32_16x16x32_f16(a0, b0, acc00, 0, 0, 0);
        acc01 = __builtin_amdgcn_mfma_f32_16x16x32_f16(a0, b1, acc01, 0, 0, 0);
        acc10 = __builtin_amdgcn_mfma_f32_16x16x32_f16(a1, b0, acc10, 0, 0, 0);
        acc11 = __builtin_amdgcn_mfma_f32_16x16x32_f16(a1, b1, acc11, 0, 0, 0);
        __syncthreads();
    }

    const int g0 = col0 + qn + fm;
    const int g1 = g0 + 16;
    const float bb0 = bi[g0] + bh[g0];
    const float bb1 = bi[g1] + bh[g1];
    const int m0 = row0 + qm + fq * 4;
    #pragma unroll
    for (int r = 0; r < 4; r++) {
        int ma = m0 + r, mb = m0 + 16 + r;
        C[((size_t)(ma >> 2) * Gn + g0) * 4 + (ma & 3)] = (_Float16)(acc00[r] + bb0);
        C[((size_t)(ma >> 2) * Gn + g1) * 4 + (ma & 3)] = (_Float16)(acc01[r] + bb1);
        C[((size_t)(mb >> 2) * Gn + g0) * 4 + (mb & 3)] = (_Float16)(acc10[r] + bb0);
        C[((size_t)(mb >> 2) * Gn + g1) * 4 + (mb & 3)] = (_Float16)(acc11[r] + bb1);
    }
}

// ---------------------------------------------------------------------------
// scan256 v4: R11 structure + quad-pre loads (4 b64 per FOUR ticks) +
// CHUNKED trajectory store (per-tick LDS staging, coalesced b128 flush every
// 16 ticks) — removes all per-tick global stores and most per-tick loads
// from the serial tick path (R11's pair-pre win showed vmem ops are on it).
// ---------------------------------------------------------------------------
__global__ __launch_bounds__(256)
__attribute__((amdgpu_waves_per_eu(1, 2)))
void scan256(
    const _Float16* __restrict__ pre,   // pre4 quad-interleaved, fp16
    const float* __restrict__ w_hh,     // [512, 128] fp32 (this layer)
    _Float16* __restrict__ hs16)        // [B, Tn, 128] fp16 out
{
    const int b    = blockIdx.x;
    const int tid  = threadIdx.x;
    const int lane = tid & 63;
    const int wv   = tid >> 6;
    const int kq   = lane & 1;              // k-half
    const int u    = wv * 32 + (lane >> 1); // hidden unit (128 unique)

    __shared__ h2 hbuf[2][Hn / 2];
    __shared__ _Float16 hstage[2][16][Hn];  // 8 KB trajectory staging
    __shared__ float lds_pad[19456];        // 76 KiB occupancy limiter

    if (pre == nullptr) {                   // never true; keeps pad live
        lds_pad[tid] = (float)tid;
        __syncthreads();
        ((float*)hs16)[tid] = lds_pad[(tid * 7) & 19455];
    }

    const float* rI = w_hh + (size_t)(0 * Hn + u) * Hn + kq * 64;
    const float* rF = w_hh + (size_t)(1 * Hn + u) * Hn + kq * 64;
    const float* rG = w_hh + (size_t)(2 * Hn + u) * Hn + kq * 64;
    const float* rO = w_hh + (size_t)(3 * Hn + u) * Hn + kq * 64;
    DECL16(wiA, rI) DECL16(wiB, (rI + 32))
    DECL16(wfA, rF) DECL16(wfB, (rF + 32))
    DECL16(wgA, rG) DECL16(wgB, (rG + 32))
    DECL16(woA, rO) DECL16(woB, (rO + 32))
    KEEP16(wiA) KEEP16(wiB) KEEP16(wfA) KEEP16(wfB)
    KEEP16(wgA) KEEP16(wgB) KEEP16(woA) KEEP16(woB)

    if (tid < Hn / 2) hbuf[0][tid] = pkh(0.f, 0.f);
    __syncthreads();

    // quad-view of pre4: qq[qr*Gn + g*128 + u] = h4{ticks 4qr..4qr+3}
    const h4* qq = (const h4*)pre + (size_t)(b * 128) * Gn + u;
    _Float16* hsb = hs16 + (size_t)b * Tn * Hn;

    // pre-mask: only the kq==0 lane of each pair carries the pre/bias seed
    const float ms = (kq == 0) ? 1.f : 0.f;

    h4 qI0 = qq[0],   qF0 = qq[128],      qG0 = qq[256],      qO0 = qq[384];
    h4 qI1 = qq[Gn],  qF1 = qq[Gn + 128], qG1 = qq[Gn + 256], qO1 = qq[Gn + 384];
    const h4* pld = qq + 2 * (size_t)Gn;

    float cr = 0.f;

    auto body = [&](int t, float vI, float vF, float vG, float vO) {
        const h2* hrow = &hbuf[t & 1][kq * 32];
        half8 hA = LD8H(hrow);      half8 hB = LD8H(hrow + 4);
        half8 hC = LD8H(hrow + 8);  half8 hD = LD8H(hrow + 12);
        half8 hE = LD8H(hrow + 16); half8 hF_ = LD8H(hrow + 20);
        half8 hG_ = LD8H(hrow + 24); half8 hH_ = LD8H(hrow + 28);
        EXTRACT16(hvA, hA, hB, hC, hD)
        EXTRACT16(hvB, hE, hF_, hG_, hH_)

        float aI = vI, aF = vF, aG = vG, aO = vO;
        DOTA(0)  DOTA(1)  DOTA(2)  DOTA(3)
        DOTA(4)  DOTA(5)  DOTA(6)  DOTA(7)
        DOTA(8)  DOTA(9)  DOTA(10) DOTA(11)
        DOTA(12) DOTA(13) DOTA(14) DOTA(15)
        DOTB(0)  DOTB(1)  DOTB(2)  DOTB(3)
        DOTB(4)  DOTB(5)  DOTB(6)  DOTB(7)
        DOTB(8)  DOTB(9)  DOTB(10) DOTB(11)
        DOTB(12) DOTB(13) DOTB(14) DOTB(15)

        DPPADD(aI, 0xB1) DPPADD(aF, 0xB1) DPPADD(aG, 0xB1) DPPADD(aO, 0xB1)

        float iv = sigm(aI);
        float fv = sigm(aF);
        float gv = tanh_fast(aG);
        float ov = sigm(aO);
        cr = fv * cr + iv * gv;
        float hnew = ov * tanh_fast(cr);
        _Float16 hh = (_Float16)hnew;
        if (kq == 0) {
            ((_Float16*)hbuf[(t + 1) & 1])[u] = hh;       // next-tick h
            hstage[(t >> 4) & 1][t & 15][u] = hh;         // traj staging
        }
        BAR_LDS();
    };

    // flush chunk ch (ticks 16ch..16ch+15) to global, coalesced b128.
    // hstage[ch&1] writes all happened before the last BAR_LDS -> visible.
    auto flush = [&](int ch) {
        const float4* src = (const float4*)&hstage[ch & 1][0][0];
        float4 v = src[tid];                  // 256 thr x 16B = 4KB
        *(float4*)(hsb + (size_t)ch * 16 * Hn + tid * 8) = v;
    };

    // 128 quads: 126 steady + 2 epilogue. Flush after every 4th quad.
    for (int qr = 0; qr < 126; qr++) {
        body(4 * qr,     ms * (float)qI0.x, ms * (float)qF0.x,
                         ms * (float)qG0.x, ms * (float)qO0.x);
        body(4 * qr + 1, ms * (float)qI0.y, ms * (float)qF0.y,
                         ms * (float)qG0.y, ms * (float)qO0.y);
        body(4 * qr + 2, ms * (float)qI0.z, ms * (float)qF0.z,
                         ms * (float)qG0.z, ms * (float)qO0.z);
        body(4 * qr + 3, ms * (float)qI0.w, ms * (float)qF0.w,
                         ms * (float)qG0.w, ms * (float)qO0.w);
        if ((qr & 3) == 3) flush(qr >> 2);
        qI0 = qI1; qF0 = qF1; qG0 = qG1; qO0 = qO1;
        qI1 = pld[0]; qF1 = pld[128]; qG1 = pld[256]; qO1 = pld[384];
        pld += Gn;
    }
    // qr = 126 (no flush: 126&3 == 2)
    body(504, ms * (float)qI0.x, ms * (float)qF0.x,
              ms * (float)qG0.x, ms * (float)qO0.x);
    body(505, ms * (float)qI0.y, ms * (float)qF0.y,
              ms * (float)qG0.y, ms * (float)qO0.y);
    body(506, ms * (float)qI0.z, ms * (float)qF0.z,
              ms * (float)qG0.z, ms * (float)qO0.z);
    body(507, ms * (float)qI0.w, ms * (float)qF0.w,
              ms * (float)qG0.w, ms * (float)qO0.w);
    qI0 = qI1; qF0 = qF1; qG0 = qG1; qO0 = qO1;
    // qr = 127
    body(508, ms * (float)qI0.x, ms * (float)qF0.x,
              ms * (float)qG0.x, ms * (float)qO0.x);
    body(509, ms * (float)qI0.y, ms * (float)qF0.y,
              ms * (float)qG0.y, ms * (float)qO0.y);
    body(510, ms * (float)qI0.z, ms * (float)qF0.z,
              ms * (float)qG0.z, ms * (float)qO0.z);
    body(511, ms * (float)qI0.w, ms * (float)qF0.w,
              ms * (float)qG0.w, ms * (float)qO0.w);
    flush(31);
}

// ---------------------------------------------------------------------------
// Attention pooling + MLP head (reads fp16 hs). One block per batch item.
// ---------------------------------------------------------------------------
__global__ __launch_bounds__(256) void head_kernel(
    const _Float16* __restrict__ hs16,
    const float* __restrict__ w_attn, const float* __restrict__ b_attn,
    const float* __restrict__ w1, const float* __restrict__ b1,
    const float* __restrict__ w2, const float* __restrict__ b2,
    float* __restrict__ out)
{
    const int b = blockIdx.x;
    const int tid = threadIdx.x;
    __shared__ h2 wa2[Hn / 2];
    __shared__ __align__(16) float sc[Tn];
    __shared__ __align__(16) float red[256];
    __shared__ __align__(16) float ctx_sh[Hn];
    __shared__ __align__(16) float h1_sh[64];

    if (tid < Hn / 2) wa2[tid] = pkh(w_attn[2 * tid], w_attn[2 * tid + 1]);
    __syncthreads();

    const _Float16* hb = hs16 + (size_t)b * Tn * Hn;

    for (int t = tid; t < Tn; t += 256) {
        const h2* hp = (const h2*)(hb + (size_t)t * Hn);
        float s = 0.f;
        #pragma unroll
        for (int k = 0; k < 64; k++) s = dot2(hp[k], wa2[k], s);
        sc[t] = s + b_attn[0];
    }
    __syncthreads();

    float m = fmaxf(sc[tid], sc[tid + 256]);
    red[tid] = m; __syncthreads();
    for (int s_ = 128; s_ > 0; s_ >>= 1) {
        if (tid < s_) red[tid] = fmaxf(red[tid], red[tid + s_]);
        __syncthreads();
    }
    float mx = red[0];
    __syncthreads();
    float e0 = __expf(sc[tid] - mx), e1 = __expf(sc[tid + 256] - mx);
    sc[tid] = e0; sc[tid + 256] = e1;
    red[tid] = e0 + e1; __syncthreads();
    for (int s_ = 128; s_ > 0; s_ >>= 1) {
        if (tid < s_) red[tid] += red[tid + s_];
        __syncthreads();
    }
    float inv = 1.f / red[0];
    __syncthreads();

    {
        int jj = tid & 127, half = tid >> 7;
        float a = 0.f;
        for (int t = half * 256; t < half * 256 + 256; t++)
            a += sc[t] * (float)hb[(size_t)t * Hn + jj];
        red[tid] = a;
        __syncthreads();
        if (tid < Hn) ctx_sh[tid] = (red[tid] + red[tid + Hn]) * inv;
        __syncthreads();
    }

    if (tid < 64) {
        const float4* wvv = (const float4*)(w1 + (size_t)tid * Hn);
        const float4* cv = (const float4*)ctx_sh;
        float s = 0.f;
        #pragma unroll
        for (int k = 0; k < 32; k++) {
            float4 a = wvv[k], c = cv[k];
            s += a.x * c.x + a.y * c.y + a.z * c.z + a.w * c.w;
        }
        h1_sh[tid] = fmaxf(s + b1[tid], 0.f);
    }
    __syncthreads();

    if (tid < 4) {
        float s = 0.f;
        const float* wvv = w2 + tid * 64;
        #pragma unroll
        for (int k = 0; k < 64; k++) s += wvv[k] * h1_sh[k];
        out[b * 4 + tid] = s + b2[tid];
    }
}

// ---------------------------------------------------------------------------
extern "C" void kernel_launch(void* const* d_in, const int* in_sizes, int n_in,
                              void* d_out, int out_size, void* d_ws, size_t ws_size,
                              hipStream_t stream)
{
    const float* x        = (const float*)d_in[0];
    const float* w_ih0    = (const float*)d_in[1];
    const float* w_ih_rest= (const float*)d_in[2];
    const float* w_hh     = (const float*)d_in[3];
    const float* b_ih     = (const float*)d_in[4];
    const float* b_hh     = (const float*)d_in[5];
    const float* w_attn   = (const float*)d_in[6];
    const float* b_attn   = (const float*)d_in[7];
    const float* w1       = (const float*)d_in[8];
    const float* b1       = (const float*)d_in[9];
    const float* w2       = (const float*)d_in[10];
    const float* b2       = (const float*)d_in[11];
    float* out = (float*)d_out;

    const size_t nHS  = (size_t)Bn * Tn * Hn;       // 8,388,608
    const size_t nPRE = (size_t)Bn * Tn * Gn;       // 33,554,432 (fp16)

    _Float16* preh = (_Float16*)d_ws;
    _Float16* hs0  = preh + nPRE;
    _Float16* hs1  = hs0 + nHS;
    _Float16* hs2  = hs1 + nHS;
    // total ~117 MB fp16

    // layer 0: A = x (fp32, converted inline), W = w_ih0 (fp32)
    gemm_pre<float><<<dim3(Bn * Tn / 64, 8), 256, 0, stream>>>(
        x, Dn, Tn * Dn, 0, 9, w_ih0, b_ih, b_hh, preh);
    scan256<<<Bn, 256, 0, stream>>>(preh, w_hh, hs0);

    // layer 1: A = hs0 (fp16), W = w_ih_rest[0] (fp32)
    gemm_pre<_Float16><<<dim3(Bn * Tn / 64, 8), 256, 0, stream>>>(
        hs0, Hn, Tn * Hn, 0, 9, w_ih_rest,
        b_ih + Gn, b_hh + Gn, preh);
    scan256<<<Bn, 256, 0, stream>>>(preh, w_hh + (size_t)Gn * Hn, hs1);

    // layer 2: A = hs1 (fp16), W = w_ih_rest[1] (fp32)
    gemm_pre<_Float16><<<dim3(Bn * Tn / 64, 8), 256, 0, stream>>>(
        hs1, Hn, Tn * Hn, 0, 9, w_ih_rest + (size_t)Gn * Hn,
        b_ih + 2 * Gn, b_hh + 2 * Gn, preh);
    scan256<<<Bn, 256, 0, stream>>>(preh, w_hh + 2 * (size_t)Gn * Hn, hs2);

    head_kernel<<<Bn, 256, 0, stream>>>(hs2, w_attn, b_attn, w1, b1, w2, b2, out);
}